// Round 1
// baseline (291.760 us; speedup 1.0000x reference)
//
#include <hip/hip_runtime.h>
#include <hip/hip_bf16.h>
#include <stdint.h>
#include <stddef.h>

// Problem constants (from reference)
#define IN_F     1024
#define OUT_F    1024
#define BATCH    4096
#define NSPLINE  8            // GRID_SIZE + SPLINE_ORDER
#define KDIM     (IN_F * 9)   // 9216 : plane 0 = silu(x), planes 1..8 = spline basis
#define GRIDPTS  12           // GRID_SIZE + 2*SPLINE_ORDER + 1

typedef __bf16 bf16;
typedef __bf16 bf16x8 __attribute__((ext_vector_type(8)));
typedef float  f32x4  __attribute__((ext_vector_type(4)));

// -------------------------------------------------------------------------
// Kernel 1: build augmented activation matrix A[BATCH][KDIM] in bf16.
//   k = i            -> silu(x[b,i])
//   k = (1+j)*IN_F+i -> B-spline basis_j(x[b,i])
// -------------------------------------------------------------------------
__global__ __launch_bounds__(256) void build_A(const float* __restrict__ x,
                                               const float* __restrict__ grid,
                                               bf16* __restrict__ A)
{
    __shared__ float g[GRIDPTS];
    if (threadIdx.x < GRIDPTS) g[threadIdx.x] = grid[threadIdx.x];  // row 0 (all rows identical)
    __syncthreads();

    const int idx = blockIdx.x * 256 + threadIdx.x;   // b*IN_F + i
    const int b = idx >> 10;
    const int i = idx & 1023;
    const float xv = x[idx];

    // order-0 indicators (11)
    float bs[11];
#pragma unroll
    for (int j = 0; j < 11; ++j)
        bs[j] = (xv >= g[j] && xv < g[j + 1]) ? 1.0f : 0.0f;

    // Cox–de Boor recurrence, exactly mirroring the reference (incl. +1e-8)
#pragma unroll
    for (int k = 1; k <= 3; ++k) {
#pragma unroll
        for (int j = 0; j < 11 - 3; ++j) {  // placeholder to keep unroll bounds constant; real bound below
        }
#pragma unroll
        for (int j = 0; j < 10; ++j) {
            if (j < 11 - k) {
                const float d0 = g[j + k]     - g[j]     + 1e-8f;
                const float d1 = g[j + k + 1] - g[j + 1] + 1e-8f;
                bs[j] = (xv - g[j]) / d0 * bs[j] + (g[j + k + 1] - xv) / d1 * bs[j + 1];
            }
        }
    }

    const float si = xv / (1.0f + __expf(-xv));   // silu

    bf16* rowp = A + (size_t)b * KDIM;
    rowp[i] = (bf16)si;
#pragma unroll
    for (int j = 0; j < NSPLINE; ++j)
        rowp[(size_t)(j + 1) * IN_F + i] = (bf16)bs[j];
}

// -------------------------------------------------------------------------
// Kernel 2: pack weights W[OUT_F][KDIM] in bf16 (scaler fused into spline w).
// -------------------------------------------------------------------------
__global__ __launch_bounds__(256) void pack_W(const float* __restrict__ bw,
                                              const float* __restrict__ sw,
                                              const float* __restrict__ sc,
                                              bf16* __restrict__ W)
{
    const int idx = blockIdx.x * 256 + threadIdx.x;   // o*IN_F + i
    const int i = idx & 1023;
    const float s = sc[idx];

    bf16* rowp = W + (size_t)(idx >> 10) * KDIM;
    rowp[i] = (bf16)bw[idx];

    const float4* swv = (const float4*)(sw + (size_t)idx * NSPLINE);
    const float4 w0 = swv[0];
    const float4 w1 = swv[1];
    rowp[(size_t)1 * IN_F + i] = (bf16)(w0.x * s);
    rowp[(size_t)2 * IN_F + i] = (bf16)(w0.y * s);
    rowp[(size_t)3 * IN_F + i] = (bf16)(w0.z * s);
    rowp[(size_t)4 * IN_F + i] = (bf16)(w0.w * s);
    rowp[(size_t)5 * IN_F + i] = (bf16)(w1.x * s);
    rowp[(size_t)6 * IN_F + i] = (bf16)(w1.y * s);
    rowp[(size_t)7 * IN_F + i] = (bf16)(w1.z * s);
    rowp[(size_t)8 * IN_F + i] = (bf16)(w1.w * s);
}

// -------------------------------------------------------------------------
// Kernel 3: C[M][N] = A[M][K] * W[N][K]^T  (both K-contiguous, bf16 -> f32)
// m97-style: 128x128 tile, BK=32, 4 waves, 4x4 16x16x32 MFMA frags/wave,
// global_load_lds width=16 staging.
// -------------------------------------------------------------------------
#define BM 128
#define BN 128
#define BK 32

#define GLOAD_LDS16(gp, lp)                                                          \
    __builtin_amdgcn_global_load_lds((const __attribute__((address_space(1))) void*)(gp), \
                                     (__attribute__((address_space(3))) void*)(lp), 16, 0, 0)

__global__ __launch_bounds__(256) void gemm_bt(const bf16* __restrict__ A,
                                               const bf16* __restrict__ B,
                                               float* __restrict__ C)
{
    __shared__ bf16 As[BM * BK];
    __shared__ bf16 Bs[BN * BK];

    const int tid  = threadIdx.x;
    const int wave = tid >> 6;
    const int lane = tid & 63;
    const int bm = blockIdx.x * BM;
    const int bn = blockIdx.y * BN;
    const int wr = (wave >> 1) * 64;   // wave row offset in tile
    const int wc = (wave & 1) * 64;    // wave col offset in tile

    f32x4 acc[4][4];
#pragma unroll
    for (int i = 0; i < 4; ++i)
#pragma unroll
        for (int j = 0; j < 4; ++j)
            acc[i][j] = (f32x4){0.f, 0.f, 0.f, 0.f};

    // staging geometry: each wave stages 32 rows (2 calls x 16 rows) of A and B
    const int srow   = lane >> 2;        // 0..15 row within 16-row group
    const int schunk = (lane & 3) * 8;   // element offset within row (8 bf16 = 16B)
    const bf16* gA0 = A + (size_t)(bm + wave * 32 + srow) * KDIM + schunk;
    const bf16* gA1 = gA0 + (size_t)16 * KDIM;
    const bf16* gB0 = B + (size_t)(bn + wave * 32 + srow) * KDIM + schunk;
    const bf16* gB1 = gB0 + (size_t)16 * KDIM;
    bf16* lA0 = &As[(wave * 32)      * BK];
    bf16* lA1 = &As[(wave * 32 + 16) * BK];
    bf16* lB0 = &Bs[(wave * 32)      * BK];
    bf16* lB1 = &Bs[(wave * 32 + 16) * BK];

    const int lrow = lane & 15;          // fragment row (A) / col (B)
    const int lk   = (lane >> 4) * 8;    // fragment k element offset

    for (int k0 = 0; k0 < KDIM; k0 += BK) {
        GLOAD_LDS16(gA0 + k0, lA0);
        GLOAD_LDS16(gA1 + k0, lA1);
        GLOAD_LDS16(gB0 + k0, lB0);
        GLOAD_LDS16(gB1 + k0, lB1);
        __syncthreads();

        bf16x8 af[4], bfr[4];
#pragma unroll
        for (int f = 0; f < 4; ++f)
            af[f] = *(const bf16x8*)&As[(wr + f * 16 + lrow) * BK + lk];
#pragma unroll
        for (int f = 0; f < 4; ++f)
            bfr[f] = *(const bf16x8*)&Bs[(wc + f * 16 + lrow) * BK + lk];

#pragma unroll
        for (int i = 0; i < 4; ++i)
#pragma unroll
            for (int j = 0; j < 4; ++j)
                acc[i][j] = __builtin_amdgcn_mfma_f32_16x16x32_bf16(af[i], bfr[j], acc[i][j], 0, 0, 0);
        __syncthreads();
    }

    // epilogue: C/D layout col = lane&15, row = (lane>>4)*4 + r  [guide m89]
    const int ccol = lane & 15;
    const int crow = (lane >> 4) * 4;
#pragma unroll
    for (int i = 0; i < 4; ++i) {
#pragma unroll
        for (int j = 0; j < 4; ++j) {
            float* cp = C + (size_t)(bm + wr + i * 16 + crow) * OUT_F + (bn + wc + j * 16 + ccol);
#pragma unroll
            for (int r = 0; r < 4; ++r)
                cp[(size_t)r * OUT_F] = acc[i][j][r];
        }
    }
}

// -------------------------------------------------------------------------
extern "C" void kernel_launch(void* const* d_in, const int* in_sizes, int n_in,
                              void* d_out, int out_size, void* d_ws, size_t ws_size,
                              hipStream_t stream)
{
    const float* x  = (const float*)d_in[0];   // (4096,1024)
    const float* bw = (const float*)d_in[1];   // (1024,1024)
    const float* sw = (const float*)d_in[2];   // (1024,1024,8)
    const float* sc = (const float*)d_in[3];   // (1024,1024)
    const float* gr = (const float*)d_in[4];   // (1024,12) all rows equal
    float* out = (float*)d_out;                // (4096,1024)

    bf16* A = (bf16*)d_ws;                          // 4096*9216*2 = 75.5 MB
    bf16* W = A + (size_t)BATCH * KDIM;             // 1024*9216*2 = 18.9 MB

    build_A<<<(BATCH * IN_F) / 256, 256, 0, stream>>>(x, gr, A);
    pack_W<<<(OUT_F * IN_F) / 256, 256, 0, stream>>>(bw, sw, sc, W);

    dim3 g(BATCH / BM, OUT_F / BN);   // 32 x 8 = 256 blocks
    gemm_bt<<<g, 256, 0, stream>>>(A, W, out);
}

// Round 2
// 156.185 us; speedup vs baseline: 1.8680x; 1.8680x over previous
//
#include <hip/hip_runtime.h>
#include <hip/hip_bf16.h>
#include <stdint.h>
#include <stddef.h>

// Problem constants (from reference)
#define IN_F     1024
#define OUT_F    1024
#define BATCH    4096
#define NSPLINE  8            // GRID_SIZE + SPLINE_ORDER
#define KDIM     (IN_F * 9)   // 9216 : plane 0 = silu(x), planes 1..8 = spline basis
#define GRIDPTS  12           // GRID_SIZE + 2*SPLINE_ORDER + 1

typedef __bf16 bf16;
typedef __bf16 bf16x8 __attribute__((ext_vector_type(8)));
typedef float  f32x4  __attribute__((ext_vector_type(4)));

// -------------------------------------------------------------------------
// Kernel 1: build augmented activation matrix A[BATCH][KDIM] in bf16.
//   k = i            -> silu(x[b,i])
//   k = (1+j)*IN_F+i -> B-spline basis_j(x[b,i])
// Cox-de Boor denominators depend only on the (uniform) grid -> precompute
// their reciprocals once per block in LDS; per-thread math is mul/fma only.
// -------------------------------------------------------------------------
__global__ __launch_bounds__(256) void build_A(const float* __restrict__ x,
                                               const float* __restrict__ grid,
                                               bf16* __restrict__ A)
{
    __shared__ float g[GRIDPTS];
    __shared__ float rec[33];   // rec[(k-1)*11 + j] = 1/(g[j+k]-g[j]+1e-8)
    if (threadIdx.x < GRIDPTS) g[threadIdx.x] = grid[threadIdx.x];  // row 0 (rows identical)
    __syncthreads();
    if (threadIdx.x < 33) {
        const int k = threadIdx.x / 11 + 1;
        const int j = threadIdx.x % 11;
        if (j + k <= 11) rec[threadIdx.x] = 1.0f / (g[j + k] - g[j] + 1e-8f);
    }
    __syncthreads();

    const int idx = blockIdx.x * 256 + threadIdx.x;   // b*IN_F + i
    const int b = idx >> 10;
    const int i = idx & 1023;
    const float xv = x[idx];

    // order-0 indicators (11)
    float bs[11];
#pragma unroll
    for (int j = 0; j < 11; ++j)
        bs[j] = (xv >= g[j] && xv < g[j + 1]) ? 1.0f : 0.0f;

    // Cox–de Boor recurrence (denominator reciprocals from LDS, broadcast)
#pragma unroll
    for (int k = 1; k <= 3; ++k) {
        const float* rk = &rec[(k - 1) * 11];
#pragma unroll
        for (int j = 0; j < 10; ++j) {
            if (j <= 10 - k) {
                bs[j] = (xv - g[j]) * rk[j] * bs[j]
                      + (g[j + k + 1] - xv) * rk[j + 1] * bs[j + 1];
            }
        }
    }

    const float si = xv / (1.0f + __expf(-xv));   // silu

    bf16* rowp = A + (size_t)b * KDIM;
    rowp[i] = (bf16)si;
#pragma unroll
    for (int j = 0; j < NSPLINE; ++j)
        rowp[(size_t)(j + 1) * IN_F + i] = (bf16)bs[j];
}

// -------------------------------------------------------------------------
// Kernel 2: pack weights W[OUT_F][KDIM] in bf16 (scaler fused into spline w).
// -------------------------------------------------------------------------
__global__ __launch_bounds__(256) void pack_W(const float* __restrict__ bw,
                                              const float* __restrict__ sw,
                                              const float* __restrict__ sc,
                                              bf16* __restrict__ W)
{
    const int idx = blockIdx.x * 256 + threadIdx.x;   // o*IN_F + i
    const int i = idx & 1023;
    const float s = sc[idx];

    bf16* rowp = W + (size_t)(idx >> 10) * KDIM;
    rowp[i] = (bf16)bw[idx];

    const float4* swv = (const float4*)(sw + (size_t)idx * NSPLINE);
    const float4 w0 = swv[0];
    const float4 w1 = swv[1];
    rowp[(size_t)1 * IN_F + i] = (bf16)(w0.x * s);
    rowp[(size_t)2 * IN_F + i] = (bf16)(w0.y * s);
    rowp[(size_t)3 * IN_F + i] = (bf16)(w0.z * s);
    rowp[(size_t)4 * IN_F + i] = (bf16)(w0.w * s);
    rowp[(size_t)5 * IN_F + i] = (bf16)(w1.x * s);
    rowp[(size_t)6 * IN_F + i] = (bf16)(w1.y * s);
    rowp[(size_t)7 * IN_F + i] = (bf16)(w1.z * s);
    rowp[(size_t)8 * IN_F + i] = (bf16)(w1.w * s);
}

// -------------------------------------------------------------------------
// Kernel 3: split-K GEMM.  C_part[z][M][N] += A[M][kslice] * W[N][kslice]^T
// m97 structure: 128x128 tile, BK=32, 4 waves, 4x4 16x16x32 MFMA frags/wave,
// global_load_lds width=16 staging. blockIdx.z selects the K-slice and the
// partial-output buffer (stride M*N floats).
// -------------------------------------------------------------------------
#define BM 128
#define BN 128
#define BK 32

#define GLOAD_LDS16(gp, lp)                                                          \
    __builtin_amdgcn_global_load_lds((const __attribute__((address_space(1))) void*)(gp), \
                                     (__attribute__((address_space(3))) void*)(lp), 16, 0, 0)

__global__ __launch_bounds__(256) void gemm_bt(const bf16* __restrict__ A,
                                               const bf16* __restrict__ B,
                                               float* __restrict__ C,
                                               int kLen)
{
    __shared__ bf16 As[BM * BK];
    __shared__ bf16 Bs[BN * BK];

    const int tid  = threadIdx.x;
    const int wave = tid >> 6;
    const int lane = tid & 63;
    const int bm = blockIdx.x * BM;
    const int bn = blockIdx.y * BN;
    const int kBase = blockIdx.z * kLen;
    const int wr = (wave >> 1) * 64;   // wave row offset in tile
    const int wc = (wave & 1) * 64;    // wave col offset in tile

    C += (size_t)blockIdx.z * BATCH * OUT_F;   // partial buffer for this K-slice

    f32x4 acc[4][4];
#pragma unroll
    for (int i = 0; i < 4; ++i)
#pragma unroll
        for (int j = 0; j < 4; ++j)
            acc[i][j] = (f32x4){0.f, 0.f, 0.f, 0.f};

    // staging geometry: each wave stages 32 rows (2 calls x 16 rows) of A and B
    const int srow   = lane >> 2;        // 0..15 row within 16-row group
    const int schunk = (lane & 3) * 8;   // element offset within row (8 bf16 = 16B)
    const bf16* gA0 = A + (size_t)(bm + wave * 32 + srow) * KDIM + schunk + kBase;
    const bf16* gA1 = gA0 + (size_t)16 * KDIM;
    const bf16* gB0 = B + (size_t)(bn + wave * 32 + srow) * KDIM + schunk + kBase;
    const bf16* gB1 = gB0 + (size_t)16 * KDIM;
    bf16* lA0 = &As[(wave * 32)      * BK];
    bf16* lA1 = &As[(wave * 32 + 16) * BK];
    bf16* lB0 = &Bs[(wave * 32)      * BK];
    bf16* lB1 = &Bs[(wave * 32 + 16) * BK];

    const int lrow = lane & 15;          // fragment row (A) / col (B)
    const int lk   = (lane >> 4) * 8;    // fragment k element offset

    for (int k0 = 0; k0 < kLen; k0 += BK) {
        GLOAD_LDS16(gA0 + k0, lA0);
        GLOAD_LDS16(gA1 + k0, lA1);
        GLOAD_LDS16(gB0 + k0, lB0);
        GLOAD_LDS16(gB1 + k0, lB1);
        __syncthreads();

        bf16x8 af[4], bfr[4];
#pragma unroll
        for (int f = 0; f < 4; ++f)
            af[f] = *(const bf16x8*)&As[(wr + f * 16 + lrow) * BK + lk];
#pragma unroll
        for (int f = 0; f < 4; ++f)
            bfr[f] = *(const bf16x8*)&Bs[(wc + f * 16 + lrow) * BK + lk];

#pragma unroll
        for (int i = 0; i < 4; ++i)
#pragma unroll
            for (int j = 0; j < 4; ++j)
                acc[i][j] = __builtin_amdgcn_mfma_f32_16x16x32_bf16(af[i], bfr[j], acc[i][j], 0, 0, 0);
        __syncthreads();
    }

    // epilogue: C/D layout col = lane&15, row = (lane>>4)*4 + r  [guide m89]
    const int ccol = lane & 15;
    const int crow = (lane >> 4) * 4;
#pragma unroll
    for (int i = 0; i < 4; ++i) {
#pragma unroll
        for (int j = 0; j < 4; ++j) {
            float* cp = C + (size_t)(bm + wr + i * 16 + crow) * OUT_F + (bn + wc + j * 16 + ccol);
#pragma unroll
            for (int r = 0; r < 4; ++r)
                cp[(size_t)r * OUT_F] = acc[i][j][r];
        }
    }
}

// -------------------------------------------------------------------------
// Kernel 4: sum nPart partial C buffers into out (float4-vectorized).
// -------------------------------------------------------------------------
__global__ __launch_bounds__(256) void reduce_partials(const float4* __restrict__ P,
                                                       float4* __restrict__ out,
                                                       int nPart, int n4)
{
    const int stride = gridDim.x * 256;
    for (int i = blockIdx.x * 256 + threadIdx.x; i < n4; i += stride) {
        float4 s = P[i];
        for (int p = 1; p < nPart; ++p) {
            const float4 q = P[(size_t)p * n4 + i];
            s.x += q.x; s.y += q.y; s.z += q.z; s.w += q.w;
        }
        out[i] = s;
    }
}

// -------------------------------------------------------------------------
extern "C" void kernel_launch(void* const* d_in, const int* in_sizes, int n_in,
                              void* d_out, int out_size, void* d_ws, size_t ws_size,
                              hipStream_t stream)
{
    const float* x  = (const float*)d_in[0];   // (4096,1024)
    const float* bw = (const float*)d_in[1];   // (1024,1024)
    const float* sw = (const float*)d_in[2];   // (1024,1024,8)
    const float* sc = (const float*)d_in[3];   // (1024,1024)
    const float* gr = (const float*)d_in[4];   // (1024,12) all rows equal
    float* out = (float*)d_out;                // (4096,1024)

    bf16* A = (bf16*)d_ws;                          // 4096*9216*2 = 75.5 MB
    bf16* W = A + (size_t)BATCH * KDIM;             // 1024*9216*2 = 18.9 MB
    float* parts = (float*)(W + (size_t)OUT_F * KDIM);

    const size_t baseBytes = ((size_t)BATCH + OUT_F) * KDIM * sizeof(bf16);
    const size_t cBytes    = (size_t)BATCH * OUT_F * sizeof(float);

    // split-K degree, gated on workspace size (ws_size is fixed -> deterministic)
    int split = 1;
    if (ws_size >= baseBytes + 4 * cBytes)      split = 4;
    else if (ws_size >= baseBytes + 2 * cBytes) split = 2;

    build_A<<<(BATCH * IN_F) / 256, 256, 0, stream>>>(x, gr, A);
    pack_W<<<(OUT_F * IN_F) / 256, 256, 0, stream>>>(bw, sw, sc, W);

    dim3 g(BATCH / BM, OUT_F / BN, split);   // 32 x 8 x split blocks
    float* gemmOut = (split > 1) ? parts : out;
    gemm_bt<<<g, 256, 0, stream>>>(A, W, gemmOut, KDIM / split);

    if (split > 1) {
        const int n4 = BATCH * OUT_F / 4;
        reduce_partials<<<2048, 256, 0, stream>>>((const float4*)parts, (float4*)out,
                                                  split, n4);
    }
}

// Round 3
// 125.991 us; speedup vs baseline: 2.3157x; 1.2397x over previous
//
#include <hip/hip_runtime.h>
#include <hip/hip_bf16.h>
#include <stdint.h>
#include <stddef.h>

// Problem constants (from reference)
#define IN_F     1024
#define OUT_F    1024
#define BATCH    4096
#define NSPLINE  8            // GRID_SIZE + SPLINE_ORDER
#define KDIM     (IN_F * 9)   // 9216 : plane 0 = silu(x), planes 1..8 = spline basis
#define GRIDPTS  12           // GRID_SIZE + 2*SPLINE_ORDER + 1

typedef __bf16 bf16;
typedef __bf16 bf16x8 __attribute__((ext_vector_type(8)));
typedef float  f32x4  __attribute__((ext_vector_type(4)));

// -------------------------------------------------------------------------
// Kernel 1: build augmented activation matrix A[BATCH][KDIM] in bf16.
// -------------------------------------------------------------------------
__global__ __launch_bounds__(256) void build_A(const float* __restrict__ x,
                                               const float* __restrict__ grid,
                                               bf16* __restrict__ A)
{
    __shared__ float g[GRIDPTS];
    __shared__ float rec[33];   // rec[(k-1)*11 + j] = 1/(g[j+k]-g[j]+1e-8)
    if (threadIdx.x < GRIDPTS) g[threadIdx.x] = grid[threadIdx.x];  // row 0 (rows identical)
    __syncthreads();
    if (threadIdx.x < 33) {
        const int k = threadIdx.x / 11 + 1;
        const int j = threadIdx.x % 11;
        if (j + k <= 11) rec[threadIdx.x] = 1.0f / (g[j + k] - g[j] + 1e-8f);
    }
    __syncthreads();

    const int idx = blockIdx.x * 256 + threadIdx.x;   // b*IN_F + i
    const int b = idx >> 10;
    const int i = idx & 1023;
    const float xv = x[idx];

    float bs[11];
#pragma unroll
    for (int j = 0; j < 11; ++j)
        bs[j] = (xv >= g[j] && xv < g[j + 1]) ? 1.0f : 0.0f;

#pragma unroll
    for (int k = 1; k <= 3; ++k) {
        const float* rk = &rec[(k - 1) * 11];
#pragma unroll
        for (int j = 0; j < 10; ++j) {
            if (j <= 10 - k) {
                bs[j] = (xv - g[j]) * rk[j] * bs[j]
                      + (g[j + k + 1] - xv) * rk[j + 1] * bs[j + 1];
            }
        }
    }

    const float si = xv / (1.0f + __expf(-xv));   // silu

    bf16* rowp = A + (size_t)b * KDIM;
    rowp[i] = (bf16)si;
#pragma unroll
    for (int j = 0; j < NSPLINE; ++j)
        rowp[(size_t)(j + 1) * IN_F + i] = (bf16)bs[j];
}

// -------------------------------------------------------------------------
// Kernel 2: pack weights W[OUT_F][KDIM] in bf16 (scaler fused into spline w).
// -------------------------------------------------------------------------
__global__ __launch_bounds__(256) void pack_W(const float* __restrict__ bw,
                                              const float* __restrict__ sw,
                                              const float* __restrict__ sc,
                                              bf16* __restrict__ W)
{
    const int idx = blockIdx.x * 256 + threadIdx.x;   // o*IN_F + i
    const int i = idx & 1023;
    const float s = sc[idx];

    bf16* rowp = W + (size_t)(idx >> 10) * KDIM;
    rowp[i] = (bf16)bw[idx];

    const float4* swv = (const float4*)(sw + (size_t)idx * NSPLINE);
    const float4 w0 = swv[0];
    const float4 w1 = swv[1];
    rowp[(size_t)1 * IN_F + i] = (bf16)(w0.x * s);
    rowp[(size_t)2 * IN_F + i] = (bf16)(w0.y * s);
    rowp[(size_t)3 * IN_F + i] = (bf16)(w0.z * s);
    rowp[(size_t)4 * IN_F + i] = (bf16)(w0.w * s);
    rowp[(size_t)5 * IN_F + i] = (bf16)(w1.x * s);
    rowp[(size_t)6 * IN_F + i] = (bf16)(w1.y * s);
    rowp[(size_t)7 * IN_F + i] = (bf16)(w1.z * s);
    rowp[(size_t)8 * IN_F + i] = (bf16)(w1.w * s);
}

// -------------------------------------------------------------------------
// Kernel 3: 256x256x64 8-phase split-K GEMM (T1+T3+T4+T5).
//   C_part[z][M][N] = A[M][kslice] * W[N][kslice]^T  (both K-contiguous)
// 512 threads = 8 waves (2M x 4N); per-wave output 128x64 (acc[8][4] f32x4).
// LDS: 8 slots x 16KB; each slot = one K-half [256 rows][32 k] bf16.
// Half stream order per K-tile t: A-kh0, B-kh0, A-kh1, B-kh1 (h = 4t+0..3).
// 4 phases/tile: P1 (kh0, M-low: 8 ds_read, 16 MFMA), P2 (kh0, M-high: 4,16),
// P3 (kh1, M-low: 8,16), P4 (kh1, M-high: 4,16).
// Staging: 1 half (2 x global_load_lds w=16) per phase at lead +6 halves;
// vmcnt(4) once per tile before P4's closing barrier (vmcnt(0) at the end).
// 64-B LDS rows make the b128 fragment reads bank-conflict-free (no swizzle).
// -------------------------------------------------------------------------
#define BM8 256
#define BN8 256
#define BK8 64

#define GLOAD_LDS16(gp, lp)                                                          \
    __builtin_amdgcn_global_load_lds((const __attribute__((address_space(1))) void*)(gp), \
                                     (__attribute__((address_space(3))) void*)(lp), 16, 0, 0)

__global__ __launch_bounds__(512, 2) void gemm8(const bf16* __restrict__ A,
                                                const bf16* __restrict__ B,
                                                float* __restrict__ C,
                                                int kLen)
{
    __shared__ bf16 lds[8 * 8192];   // 8 half-slots x 16 KB = 128 KB

    const int tid  = threadIdx.x;
    const int wave = tid >> 6;
    const int lane = tid & 63;

    // bijective XCD swizzle (gridDim.x % 8 == 0 for all split degrees here)
    const int nwg  = gridDim.x;
    const int q    = nwg >> 3;
    const int wgid = (blockIdx.x & 7) * q + (blockIdx.x >> 3);
    const int nxy  = (BATCH / BM8) * (OUT_F / BN8);   // 16*4 = 64
    const int z    = wgid / nxy;
    const int rem  = wgid - z * nxy;
    const int by   = rem >> 4;           // 0..3
    const int bx   = rem & 15;           // 0..15

    const int bm = bx * BM8;
    const int bn = by * BN8;
    const int kBase = z * kLen;
    C += (size_t)z * BATCH * OUT_F;      // partial buffer (z=0 when split=1)

    const int wr = (wave >> 2) * 128;    // 2 M-waves
    const int wc = (wave & 3) * 64;      // 4 N-waves

    f32x4 acc[8][4] = {};

    const int NT   = kLen / BK8;
    const int hmax = 4 * NT;

    // staging geometry: tid covers row tid/4, k-chunk (tid%4)*8 of each half
    const int srow = tid >> 2;           // 0..127
    const int sch  = (tid & 3) * 8;
    const bf16* baseA = A + (size_t)(bm + srow) * KDIM + kBase + sch;
    const bf16* baseB = B + (size_t)(bn + srow) * KDIM + kBase + sch;
    const size_t rstep = (size_t)128 * KDIM;
    bf16* ldsw = &lds[wave * 512];       // wave-uniform dest segment

    auto stage = [&](int h) {
        if (h < hmax) {
            const int t   = h >> 2;
            const int th  = h & 3;
            const int kof = t * BK8 + ((th >> 1) ? 32 : 0);
            const bf16* src = (th & 1) ? baseB : baseA;
            bf16* l0 = ldsw + (h & 7) * 8192;
            GLOAD_LDS16(src + kof, l0);
            GLOAD_LDS16(src + kof + rstep, l0 + 4096);
        }
    };

    // prologue: stage halves 0..5, wait for halves 0..3
    for (int h = 0; h < 6; ++h) stage(h);
    asm volatile("s_waitcnt vmcnt(4)" ::: "memory");
    __builtin_amdgcn_s_barrier();

    const int rowk = lane & 15;
    const int kofe = (lane >> 4) * 8;    // k-element offset within 32-wide half

#define LDSFRAG(slot, row) (*(const bf16x8*)&lds[(slot) * 8192 + (row) * 32 + kofe])

    for (int t = 0; t < NT; ++t) {
        const int h0  = 4 * t;
        const int sA0 = (h0 + 0) & 7, sB0 = (h0 + 1) & 7;
        const int sA1 = (h0 + 2) & 7, sB1 = (h0 + 3) & 7;
        bf16x8 a[4], b[4];

        // ---- phase 1: kh0, M-low ----
#pragma unroll
        for (int m = 0; m < 4; ++m) a[m] = LDSFRAG(sA0, wr + m * 16 + rowk);
#pragma unroll
        for (int n = 0; n < 4; ++n) b[n] = LDSFRAG(sB0, wc + n * 16 + rowk);
        stage(h0 + 6);
        __builtin_amdgcn_s_barrier();
        asm volatile("s_waitcnt lgkmcnt(0)" ::: "memory");
        __builtin_amdgcn_sched_barrier(0);
        __builtin_amdgcn_s_setprio(1);
#pragma unroll
        for (int m = 0; m < 4; ++m)
#pragma unroll
            for (int n = 0; n < 4; ++n)
                acc[m][n] = __builtin_amdgcn_mfma_f32_16x16x32_bf16(a[m], b[n], acc[m][n], 0, 0, 0);
        __builtin_amdgcn_s_setprio(0);
        __builtin_amdgcn_s_barrier();

        // ---- phase 2: kh0, M-high (reuse b) ----
#pragma unroll
        for (int m = 0; m < 4; ++m) a[m] = LDSFRAG(sA0, wr + 64 + m * 16 + rowk);
        stage(h0 + 7);
        __builtin_amdgcn_s_barrier();
        asm volatile("s_waitcnt lgkmcnt(0)" ::: "memory");
        __builtin_amdgcn_sched_barrier(0);
        __builtin_amdgcn_s_setprio(1);
#pragma unroll
        for (int m = 0; m < 4; ++m)
#pragma unroll
            for (int n = 0; n < 4; ++n)
                acc[4 + m][n] = __builtin_amdgcn_mfma_f32_16x16x32_bf16(a[m], b[n], acc[4 + m][n], 0, 0, 0);
        __builtin_amdgcn_s_setprio(0);
        __builtin_amdgcn_s_barrier();

        // ---- phase 3: kh1, M-low ----
#pragma unroll
        for (int m = 0; m < 4; ++m) a[m] = LDSFRAG(sA1, wr + m * 16 + rowk);
#pragma unroll
        for (int n = 0; n < 4; ++n) b[n] = LDSFRAG(sB1, wc + n * 16 + rowk);
        stage(h0 + 8);
        __builtin_amdgcn_s_barrier();
        asm volatile("s_waitcnt lgkmcnt(0)" ::: "memory");
        __builtin_amdgcn_sched_barrier(0);
        __builtin_amdgcn_s_setprio(1);
#pragma unroll
        for (int m = 0; m < 4; ++m)
#pragma unroll
            for (int n = 0; n < 4; ++n)
                acc[m][n] = __builtin_amdgcn_mfma_f32_16x16x32_bf16(a[m], b[n], acc[m][n], 0, 0, 0);
        __builtin_amdgcn_s_setprio(0);
        __builtin_amdgcn_s_barrier();

        // ---- phase 4: kh1, M-high (reuse b) ----
#pragma unroll
        for (int m = 0; m < 4; ++m) a[m] = LDSFRAG(sA1, wr + 64 + m * 16 + rowk);
        stage(h0 + 9);
        __builtin_amdgcn_s_barrier();
        asm volatile("s_waitcnt lgkmcnt(0)" ::: "memory");
        __builtin_amdgcn_sched_barrier(0);
        __builtin_amdgcn_s_setprio(1);
#pragma unroll
        for (int m = 0; m < 4; ++m)
#pragma unroll
            for (int n = 0; n < 4; ++n)
                acc[4 + m][n] = __builtin_amdgcn_mfma_f32_16x16x32_bf16(a[m], b[n], acc[4 + m][n], 0, 0, 0);
        __builtin_amdgcn_s_setprio(0);
        // per-tile counted wait: next tile's 4 halves complete; never 0 mid-loop
        if (t < NT - 2)       asm volatile("s_waitcnt vmcnt(4)" ::: "memory");
        else if (t == NT - 2) asm volatile("s_waitcnt vmcnt(0)" ::: "memory");
        __builtin_amdgcn_s_barrier();
    }
#undef LDSFRAG

    // epilogue: C/D layout col = lane&15, row = (lane>>4)*4 + r
    const int ccol = lane & 15;
    const int crow = (lane >> 4) * 4;
#pragma unroll
    for (int mf = 0; mf < 8; ++mf) {
#pragma unroll
        for (int nf = 0; nf < 4; ++nf) {
            float* cp = C + (size_t)(bm + wr + mf * 16 + crow) * OUT_F + (bn + wc + nf * 16 + ccol);
#pragma unroll
            for (int r = 0; r < 4; ++r)
                cp[(size_t)r * OUT_F] = acc[mf][nf][r];
        }
    }
}

// -------------------------------------------------------------------------
// Kernel 4: sum nPart partial C buffers into out (float4-vectorized).
// -------------------------------------------------------------------------
__global__ __launch_bounds__(256) void reduce_partials(const float4* __restrict__ P,
                                                       float4* __restrict__ out,
                                                       int nPart, int n4)
{
    const int stride = gridDim.x * 256;
    for (int i = blockIdx.x * 256 + threadIdx.x; i < n4; i += stride) {
        float4 s = P[i];
        for (int p = 1; p < nPart; ++p) {
            const float4 q = P[(size_t)p * n4 + i];
            s.x += q.x; s.y += q.y; s.z += q.z; s.w += q.w;
        }
        out[i] = s;
    }
}

// -------------------------------------------------------------------------
extern "C" void kernel_launch(void* const* d_in, const int* in_sizes, int n_in,
                              void* d_out, int out_size, void* d_ws, size_t ws_size,
                              hipStream_t stream)
{
    const float* x  = (const float*)d_in[0];   // (4096,1024)
    const float* bw = (const float*)d_in[1];   // (1024,1024)
    const float* sw = (const float*)d_in[2];   // (1024,1024,8)
    const float* sc = (const float*)d_in[3];   // (1024,1024)
    const float* gr = (const float*)d_in[4];   // (1024,12) all rows equal
    float* out = (float*)d_out;                // (4096,1024)

    bf16* A = (bf16*)d_ws;                          // 4096*9216*2 = 75.5 MB
    bf16* W = A + (size_t)BATCH * KDIM;             // 1024*9216*2 = 18.9 MB
    float* parts = (float*)(W + (size_t)OUT_F * KDIM);

    const size_t baseBytes = ((size_t)BATCH + OUT_F) * KDIM * sizeof(bf16);
    const size_t cBytes    = (size_t)BATCH * OUT_F * sizeof(float);

    // split-K degree, gated on workspace size (ws_size fixed -> deterministic)
    int split = 1;
    if (ws_size >= baseBytes + 4 * cBytes)      split = 4;
    else if (ws_size >= baseBytes + 2 * cBytes) split = 2;

    build_A<<<(BATCH * IN_F) / 256, 256, 0, stream>>>(x, gr, A);
    pack_W<<<(OUT_F * IN_F) / 256, 256, 0, stream>>>(bw, sw, sc, W);

    const int nblk = (BATCH / BM8) * (OUT_F / BN8) * split;   // 64*split
    float* gemmOut = (split > 1) ? parts : out;
    gemm8<<<nblk, 512, 0, stream>>>(A, W, gemmOut, KDIM / split);

    if (split > 1) {
        const int n4 = BATCH * OUT_F / 4;
        reduce_partials<<<2048, 256, 0, stream>>>((const float4*)parts, (float4*)out,
                                                  split, n4);
    }
}

// Round 4
// 122.853 us; speedup vs baseline: 2.3749x; 1.0255x over previous
//
#include <hip/hip_runtime.h>
#include <hip/hip_bf16.h>
#include <stdint.h>
#include <stddef.h>

// Problem constants (from reference)
#define IN_F     1024
#define OUT_F    1024
#define BATCH    4096
#define NSPLINE  8            // GRID_SIZE + SPLINE_ORDER
#define KDIM     (IN_F * 9)   // 9216 : plane 0 = silu(x), planes 1..8 = spline basis
#define GRIDPTS  12           // GRID_SIZE + 2*SPLINE_ORDER + 1

typedef __bf16 bf16;
typedef __bf16 bf16x8 __attribute__((ext_vector_type(8)));
typedef float  f32x4  __attribute__((ext_vector_type(4)));

// -------------------------------------------------------------------------
// Kernel 1: build augmented activation matrix A[BATCH][KDIM] in bf16.
// -------------------------------------------------------------------------
__global__ __launch_bounds__(256) void build_A(const float* __restrict__ x,
                                               const float* __restrict__ grid,
                                               bf16* __restrict__ A)
{
    __shared__ float g[GRIDPTS];
    __shared__ float rec[33];   // rec[(k-1)*11 + j] = 1/(g[j+k]-g[j]+1e-8)
    if (threadIdx.x < GRIDPTS) g[threadIdx.x] = grid[threadIdx.x];  // row 0 (rows identical)
    __syncthreads();
    if (threadIdx.x < 33) {
        const int k = threadIdx.x / 11 + 1;
        const int j = threadIdx.x % 11;
        if (j + k <= 11) rec[threadIdx.x] = 1.0f / (g[j + k] - g[j] + 1e-8f);
    }
    __syncthreads();

    const int idx = blockIdx.x * 256 + threadIdx.x;   // b*IN_F + i
    const int b = idx >> 10;
    const int i = idx & 1023;
    const float xv = x[idx];

    float bs[11];
#pragma unroll
    for (int j = 0; j < 11; ++j)
        bs[j] = (xv >= g[j] && xv < g[j + 1]) ? 1.0f : 0.0f;

#pragma unroll
    for (int k = 1; k <= 3; ++k) {
        const float* rk = &rec[(k - 1) * 11];
#pragma unroll
        for (int j = 0; j < 10; ++j) {
            if (j <= 10 - k) {
                bs[j] = (xv - g[j]) * rk[j] * bs[j]
                      + (g[j + k + 1] - xv) * rk[j + 1] * bs[j + 1];
            }
        }
    }

    const float si = xv / (1.0f + __expf(-xv));   // silu

    bf16* rowp = A + (size_t)b * KDIM;
    rowp[i] = (bf16)si;
#pragma unroll
    for (int j = 0; j < NSPLINE; ++j)
        rowp[(size_t)(j + 1) * IN_F + i] = (bf16)bs[j];
}

// -------------------------------------------------------------------------
// Kernel 2: pack weights W[OUT_F][KDIM] in bf16 (scaler fused into spline w).
// -------------------------------------------------------------------------
__global__ __launch_bounds__(256) void pack_W(const float* __restrict__ bw,
                                              const float* __restrict__ sw,
                                              const float* __restrict__ sc,
                                              bf16* __restrict__ W)
{
    const int idx = blockIdx.x * 256 + threadIdx.x;   // o*IN_F + i
    const int i = idx & 1023;
    const float s = sc[idx];

    bf16* rowp = W + (size_t)(idx >> 10) * KDIM;
    rowp[i] = (bf16)bw[idx];

    const float4* swv = (const float4*)(sw + (size_t)idx * NSPLINE);
    const float4 w0 = swv[0];
    const float4 w1 = swv[1];
    rowp[(size_t)1 * IN_F + i] = (bf16)(w0.x * s);
    rowp[(size_t)2 * IN_F + i] = (bf16)(w0.y * s);
    rowp[(size_t)3 * IN_F + i] = (bf16)(w0.z * s);
    rowp[(size_t)4 * IN_F + i] = (bf16)(w0.w * s);
    rowp[(size_t)5 * IN_F + i] = (bf16)(w1.x * s);
    rowp[(size_t)6 * IN_F + i] = (bf16)(w1.y * s);
    rowp[(size_t)7 * IN_F + i] = (bf16)(w1.z * s);
    rowp[(size_t)8 * IN_F + i] = (bf16)(w1.w * s);
}

// -------------------------------------------------------------------------
// Kernel 3: 256x256x64 8-phase split-K GEMM (T1+T2+T3+T4+T5).
//   C_part[z][M][N] = A[M][kslice] * W[N][kslice]^T  (both K-contiguous)
// 512 threads = 8 waves (2M x 4N); per-wave output 128x64 (acc[8][4] f32x4).
// LDS: 8 slots x 16KB; each slot = one K-half [256 rows][32 k] bf16.
//
// T2 bank swizzle for 64-B rows: physical 16-B slot = c ^ ((row>>1)&3).
//   bank-group = (16*row + 4*slotPhys) & 31 -> 8 consecutive rows at fixed
//   logical slot cover all 8 groups once = 2 words/bank/sub-pass (minimum).
// Both-sides-or-neither (rule #21): LDS dest of global_load_lds stays
// linear; the GLOBAL source k-chunk is pre-permuted per lane
//   (chunk = (l&3) ^ ((l>>3)&3), same 64-B row segment -> coalescing kept),
// and fragment reads apply the same XOR.
// -------------------------------------------------------------------------
#define BM8 256
#define BN8 256
#define BK8 64

#define GLOAD_LDS16(gp, lp)                                                          \
    __builtin_amdgcn_global_load_lds((const __attribute__((address_space(1))) void*)(gp), \
                                     (__attribute__((address_space(3))) void*)(lp), 16, 0, 0)

__global__ __launch_bounds__(512, 2) void gemm8(const bf16* __restrict__ A,
                                                const bf16* __restrict__ B,
                                                float* __restrict__ C,
                                                int kLen)
{
    __shared__ bf16 lds[8 * 8192];   // 8 half-slots x 16 KB = 128 KB

    const int tid  = threadIdx.x;
    const int wave = tid >> 6;
    const int lane = tid & 63;

    // bijective XCD swizzle (gridDim.x % 8 == 0 for all split degrees here)
    const int nwg  = gridDim.x;
    const int q    = nwg >> 3;
    const int wgid = (blockIdx.x & 7) * q + (blockIdx.x >> 3);
    const int nxy  = (BATCH / BM8) * (OUT_F / BN8);   // 16*4 = 64
    const int z    = wgid / nxy;
    const int rem  = wgid - z * nxy;
    const int by   = rem >> 4;           // 0..3
    const int bx   = rem & 15;           // 0..15

    const int bm = bx * BM8;
    const int bn = by * BN8;
    const int kBase = z * kLen;
    C += (size_t)z * BATCH * OUT_F;      // partial buffer (z=0 when split=1)

    const int wr = (wave >> 2) * 128;    // 2 M-waves
    const int wc = (wave & 3) * 64;      // 4 N-waves

    f32x4 acc[8][4] = {};

    const int NT   = kLen / BK8;
    const int hmax = 4 * NT;

    // staging geometry: tid covers row tid/4; global k-chunk pre-swizzled so
    // that the linear LDS write lands data where the swizzled reader expects.
    const int srow = tid >> 2;           // 0..127
    const int sch  = (((tid & 3) ^ ((tid >> 3) & 3))) * 8;
    const bf16* baseA = A + (size_t)(bm + srow) * KDIM + kBase + sch;
    const bf16* baseB = B + (size_t)(bn + srow) * KDIM + kBase + sch;
    const size_t rstep = (size_t)128 * KDIM;
    bf16* ldsw = &lds[wave * 512];       // wave-uniform dest segment

    auto stage = [&](int h) {
        if (h < hmax) {
            const int t   = h >> 2;
            const int th  = h & 3;
            const int kof = t * BK8 + ((th >> 1) ? 32 : 0);
            const bf16* src = (th & 1) ? baseB : baseA;
            bf16* l0 = ldsw + (h & 7) * 8192;
            GLOAD_LDS16(src + kof, l0);
            GLOAD_LDS16(src + kof + rstep, l0 + 4096);
        }
    };

    // prologue: stage halves 0..5, wait for halves 0..3
    for (int h = 0; h < 6; ++h) stage(h);
    asm volatile("s_waitcnt vmcnt(4)" ::: "memory");
    __builtin_amdgcn_s_barrier();

    const int rowk = lane & 15;
    const int kc   = lane >> 4;          // logical 8-elem k-chunk 0..3

    // swizzled fragment read: row's k-chunk kc lives at slot kc ^ ((row>>1)&3)
#define LDSFRAG(slot, row) (*(const bf16x8*)&lds[(slot) * 8192 + (row) * 32 + \
                               ((kc ^ (((row) >> 1) & 3)) * 8)])

    for (int t = 0; t < NT; ++t) {
        const int h0  = 4 * t;
        const int sA0 = (h0 + 0) & 7, sB0 = (h0 + 1) & 7;
        const int sA1 = (h0 + 2) & 7, sB1 = (h0 + 3) & 7;
        bf16x8 a[4], b[4];

        // ---- phase 1: kh0, M-low ----
#pragma unroll
        for (int m = 0; m < 4; ++m) a[m] = LDSFRAG(sA0, wr + m * 16 + rowk);
#pragma unroll
        for (int n = 0; n < 4; ++n) b[n] = LDSFRAG(sB0, wc + n * 16 + rowk);
        stage(h0 + 6);
        __builtin_amdgcn_s_barrier();
        asm volatile("s_waitcnt lgkmcnt(0)" ::: "memory");
        __builtin_amdgcn_sched_barrier(0);
        __builtin_amdgcn_s_setprio(1);
#pragma unroll
        for (int m = 0; m < 4; ++m)
#pragma unroll
            for (int n = 0; n < 4; ++n)
                acc[m][n] = __builtin_amdgcn_mfma_f32_16x16x32_bf16(a[m], b[n], acc[m][n], 0, 0, 0);
        __builtin_amdgcn_s_setprio(0);
        __builtin_amdgcn_s_barrier();

        // ---- phase 2: kh0, M-high (reuse b) ----
#pragma unroll
        for (int m = 0; m < 4; ++m) a[m] = LDSFRAG(sA0, wr + 64 + m * 16 + rowk);
        stage(h0 + 7);
        __builtin_amdgcn_s_barrier();
        asm volatile("s_waitcnt lgkmcnt(0)" ::: "memory");
        __builtin_amdgcn_sched_barrier(0);
        __builtin_amdgcn_s_setprio(1);
#pragma unroll
        for (int m = 0; m < 4; ++m)
#pragma unroll
            for (int n = 0; n < 4; ++n)
                acc[4 + m][n] = __builtin_amdgcn_mfma_f32_16x16x32_bf16(a[m], b[n], acc[4 + m][n], 0, 0, 0);
        __builtin_amdgcn_s_setprio(0);
        __builtin_amdgcn_s_barrier();

        // ---- phase 3: kh1, M-low ----
#pragma unroll
        for (int m = 0; m < 4; ++m) a[m] = LDSFRAG(sA1, wr + m * 16 + rowk);
#pragma unroll
        for (int n = 0; n < 4; ++n) b[n] = LDSFRAG(sB1, wc + n * 16 + rowk);
        stage(h0 + 8);
        __builtin_amdgcn_s_barrier();
        asm volatile("s_waitcnt lgkmcnt(0)" ::: "memory");
        __builtin_amdgcn_sched_barrier(0);
        __builtin_amdgcn_s_setprio(1);
#pragma unroll
        for (int m = 0; m < 4; ++m)
#pragma unroll
            for (int n = 0; n < 4; ++n)
                acc[m][n] = __builtin_amdgcn_mfma_f32_16x16x32_bf16(a[m], b[n], acc[m][n], 0, 0, 0);
        __builtin_amdgcn_s_setprio(0);
        __builtin_amdgcn_s_barrier();

        // ---- phase 4: kh1, M-high (reuse b) ----
#pragma unroll
        for (int m = 0; m < 4; ++m) a[m] = LDSFRAG(sA1, wr + 64 + m * 16 + rowk);
        stage(h0 + 9);
        __builtin_amdgcn_s_barrier();
        asm volatile("s_waitcnt lgkmcnt(0)" ::: "memory");
        __builtin_amdgcn_sched_barrier(0);
        __builtin_amdgcn_s_setprio(1);
#pragma unroll
        for (int m = 0; m < 4; ++m)
#pragma unroll
            for (int n = 0; n < 4; ++n)
                acc[4 + m][n] = __builtin_amdgcn_mfma_f32_16x16x32_bf16(a[m], b[n], acc[4 + m][n], 0, 0, 0);
        __builtin_amdgcn_s_setprio(0);
        // per-tile counted wait: next tile's 4 halves complete; never 0 mid-loop
        if (t < NT - 2)       asm volatile("s_waitcnt vmcnt(4)" ::: "memory");
        else if (t == NT - 2) asm volatile("s_waitcnt vmcnt(0)" ::: "memory");
        __builtin_amdgcn_s_barrier();
    }
#undef LDSFRAG

    // epilogue: C/D layout col = lane&15, row = (lane>>4)*4 + r
    const int ccol = lane & 15;
    const int crow = (lane >> 4) * 4;
#pragma unroll
    for (int mf = 0; mf < 8; ++mf) {
#pragma unroll
        for (int nf = 0; nf < 4; ++nf) {
            float* cp = C + (size_t)(bm + wr + mf * 16 + crow) * OUT_F + (bn + wc + nf * 16 + ccol);
#pragma unroll
            for (int r = 0; r < 4; ++r)
                cp[(size_t)r * OUT_F] = acc[mf][nf][r];
        }
    }
}

// -------------------------------------------------------------------------
// Kernel 4: sum nPart partial C buffers into out (float4-vectorized).
// -------------------------------------------------------------------------
__global__ __launch_bounds__(256) void reduce_partials(const float4* __restrict__ P,
                                                       float4* __restrict__ out,
                                                       int nPart, int n4)
{
    const int stride = gridDim.x * 256;
    for (int i = blockIdx.x * 256 + threadIdx.x; i < n4; i += stride) {
        float4 s = P[i];
        for (int p = 1; p < nPart; ++p) {
            const float4 q = P[(size_t)p * n4 + i];
            s.x += q.x; s.y += q.y; s.z += q.z; s.w += q.w;
        }
        out[i] = s;
    }
}

// -------------------------------------------------------------------------
extern "C" void kernel_launch(void* const* d_in, const int* in_sizes, int n_in,
                              void* d_out, int out_size, void* d_ws, size_t ws_size,
                              hipStream_t stream)
{
    const float* x  = (const float*)d_in[0];   // (4096,1024)
    const float* bw = (const float*)d_in[1];   // (1024,1024)
    const float* sw = (const float*)d_in[2];   // (1024,1024,8)
    const float* sc = (const float*)d_in[3];   // (1024,1024)
    const float* gr = (const float*)d_in[4];   // (1024,12) all rows equal
    float* out = (float*)d_out;                // (4096,1024)

    bf16* A = (bf16*)d_ws;                          // 4096*9216*2 = 75.5 MB
    bf16* W = A + (size_t)BATCH * KDIM;             // 1024*9216*2 = 18.9 MB
    float* parts = (float*)(W + (size_t)OUT_F * KDIM);

    const size_t baseBytes = ((size_t)BATCH + OUT_F) * KDIM * sizeof(bf16);
    const size_t cBytes    = (size_t)BATCH * OUT_F * sizeof(float);

    // split-K degree, gated on workspace size (ws_size fixed -> deterministic)
    int split = 1;
    if (ws_size >= baseBytes + 4 * cBytes)      split = 4;
    else if (ws_size >= baseBytes + 2 * cBytes) split = 2;

    build_A<<<(BATCH * IN_F) / 256, 256, 0, stream>>>(x, gr, A);
    pack_W<<<(OUT_F * IN_F) / 256, 256, 0, stream>>>(bw, sw, sc, W);

    const int nblk = (BATCH / BM8) * (OUT_F / BN8) * split;   // 64*split
    float* gemmOut = (split > 1) ? parts : out;
    gemm8<<<nblk, 512, 0, stream>>>(A, W, gemmOut, KDIM / split);

    if (split > 1) {
        const int n4 = BATCH * OUT_F / 4;
        reduce_partials<<<2048, 256, 0, stream>>>((const float4*)parts, (float4*)out,
                                                  split, n4);
    }
}

// Round 6
// 122.167 us; speedup vs baseline: 2.3882x; 1.0056x over previous
//
#include <hip/hip_runtime.h>
#include <hip/hip_bf16.h>
#include <stdint.h>
#include <stddef.h>

// Problem constants (from reference)
#define IN_F     1024
#define OUT_F    1024
#define BATCH    4096
#define NSPLINE  8            // GRID_SIZE + SPLINE_ORDER
#define KDIM     (IN_F * 9)   // 9216 : plane 0 = silu(x), planes 1..8 = spline basis
#define GRIDPTS  12           // GRID_SIZE + 2*SPLINE_ORDER + 1

typedef __bf16 bf16;
typedef __bf16 bf16x8 __attribute__((ext_vector_type(8)));
typedef float  f32x4  __attribute__((ext_vector_type(4)));

// -------------------------------------------------------------------------
// Kernel 1: build augmented activation matrix A[BATCH][KDIM] in bf16.
// -------------------------------------------------------------------------
__global__ __launch_bounds__(256) void build_A(const float* __restrict__ x,
                                               const float* __restrict__ grid,
                                               bf16* __restrict__ A)
{
    __shared__ float g[GRIDPTS];
    __shared__ float rec[33];   // rec[(k-1)*11 + j] = 1/(g[j+k]-g[j]+1e-8)
    if (threadIdx.x < GRIDPTS) g[threadIdx.x] = grid[threadIdx.x];  // row 0 (rows identical)
    __syncthreads();
    if (threadIdx.x < 33) {
        const int k = threadIdx.x / 11 + 1;
        const int j = threadIdx.x % 11;
        if (j + k <= 11) rec[threadIdx.x] = 1.0f / (g[j + k] - g[j] + 1e-8f);
    }
    __syncthreads();

    const int idx = blockIdx.x * 256 + threadIdx.x;   // b*IN_F + i
    const int b = idx >> 10;
    const int i = idx & 1023;
    const float xv = x[idx];

    float bs[11];
#pragma unroll
    for (int j = 0; j < 11; ++j)
        bs[j] = (xv >= g[j] && xv < g[j + 1]) ? 1.0f : 0.0f;

#pragma unroll
    for (int k = 1; k <= 3; ++k) {
        const float* rk = &rec[(k - 1) * 11];
#pragma unroll
        for (int j = 0; j < 10; ++j) {
            if (j <= 10 - k) {
                bs[j] = (xv - g[j]) * rk[j] * bs[j]
                      + (g[j + k + 1] - xv) * rk[j + 1] * bs[j + 1];
            }
        }
    }

    const float si = xv / (1.0f + __expf(-xv));   // silu

    bf16* rowp = A + (size_t)b * KDIM;
    rowp[i] = (bf16)si;
#pragma unroll
    for (int j = 0; j < NSPLINE; ++j)
        rowp[(size_t)(j + 1) * IN_F + i] = (bf16)bs[j];
}

// -------------------------------------------------------------------------
// Kernel 2: pack weights W[OUT_F][KDIM] in bf16 (scaler fused into spline w).
// -------------------------------------------------------------------------
__global__ __launch_bounds__(256) void pack_W(const float* __restrict__ bw,
                                              const float* __restrict__ sw,
                                              const float* __restrict__ sc,
                                              bf16* __restrict__ W)
{
    const int idx = blockIdx.x * 256 + threadIdx.x;   // o*IN_F + i
    const int i = idx & 1023;
    const float s = sc[idx];

    bf16* rowp = W + (size_t)(idx >> 10) * KDIM;
    rowp[i] = (bf16)bw[idx];

    const float4* swv = (const float4*)(sw + (size_t)idx * NSPLINE);
    const float4 w0 = swv[0];
    const float4 w1 = swv[1];
    rowp[(size_t)1 * IN_F + i] = (bf16)(w0.x * s);
    rowp[(size_t)2 * IN_F + i] = (bf16)(w0.y * s);
    rowp[(size_t)3 * IN_F + i] = (bf16)(w0.z * s);
    rowp[(size_t)4 * IN_F + i] = (bf16)(w0.w * s);
    rowp[(size_t)5 * IN_F + i] = (bf16)(w1.x * s);
    rowp[(size_t)6 * IN_F + i] = (bf16)(w1.y * s);
    rowp[(size_t)7 * IN_F + i] = (bf16)(w1.z * s);
    rowp[(size_t)8 * IN_F + i] = (bf16)(w1.w * s);
}

// -------------------------------------------------------------------------
// Kernel 3: 256x256x64 pipelined 4-phase split-K GEMM (T1+T2+T3+T4+T5).
//   C_part[z][M][N] = A[M][kslice] * W[N][kslice]^T  (both K-contiguous)
// 512 threads = 8 waves (2M x 4N); per-wave output 128x64 (acc[8][4] f32x4).
// LDS: 8 slots x 16KB; slot = one K-half [256 rows][32 k] bf16, swizzled
// (T2): physical 16-B k-chunk = kc ^ ((row>>1)&3); global source
// pre-permuted per lane so linear global_load_lds lands data where the
// swizzled reader expects (rule #21).
//
// Round 5/6: cross-phase read pipelining. Each phase issues the NEXT
// phase's ds_reads before its own MFMA block; the compiler's automatic
// wait before the MFMAs is then a COUNTED lgkmcnt (producers done,
// next-phase reads still in flight) instead of a drain. One barrier per
// phase. Hazard trace: every slot's reads complete (consuming phase's
// counted wait) >= one barrier before that slot's overwriting stage();
// next-tile phase-1 reads are issued only AFTER the per-tile vmcnt(4)
// (halves <= 4t+7 landed).
// -------------------------------------------------------------------------
#define BM8 256
#define BN8 256
#define BK8 64

#define GLOAD_LDS16(gp, lp)                                                          \
    __builtin_amdgcn_global_load_lds((const __attribute__((address_space(1))) void*)(gp), \
                                     (__attribute__((address_space(3))) void*)(lp), 16, 0, 0)

__global__ __launch_bounds__(512, 2) void gemm8(const bf16* __restrict__ A,
                                                const bf16* __restrict__ B,
                                                float* __restrict__ C,
                                                int kLen)
{
    __shared__ bf16 lds[8 * 8192];   // 8 half-slots x 16 KB = 128 KB

    const int tid  = threadIdx.x;
    const int wave = tid >> 6;
    const int lane = tid & 63;

    // bijective XCD swizzle (gridDim.x % 8 == 0 for all split degrees here)
    const int nwg  = gridDim.x;
    const int q    = nwg >> 3;
    const int wgid = (blockIdx.x & 7) * q + (blockIdx.x >> 3);
    const int nxy  = (BATCH / BM8) * (OUT_F / BN8);   // 16*4 = 64
    const int z    = wgid / nxy;
    const int rem  = wgid - z * nxy;
    const int by   = rem >> 4;           // 0..3
    const int bx   = rem & 15;           // 0..15

    const int bm = bx * BM8;
    const int bcol = by * BN8;
    const int kBase = z * kLen;
    C += (size_t)z * BATCH * OUT_F;      // partial buffer (z=0 when split=1)

    const int wr = (wave >> 2) * 128;    // 2 M-waves
    const int wc = (wave & 3) * 64;      // 4 N-waves

    f32x4 acc[8][4] = {};

    const int NT   = kLen / BK8;
    const int hmax = 4 * NT;

    // staging geometry: tid covers row tid/4; global k-chunk pre-swizzled so
    // that the linear LDS write lands data where the swizzled reader expects.
    const int srow = tid >> 2;           // 0..127
    const int sch  = (((tid & 3) ^ ((tid >> 3) & 3))) * 8;
    const bf16* baseA = A + (size_t)(bm + srow) * KDIM + kBase + sch;
    const bf16* baseB = B + (size_t)(bcol + srow) * KDIM + kBase + sch;
    const size_t rstep = (size_t)128 * KDIM;
    bf16* ldsw = &lds[wave * 512];       // wave-uniform dest segment

    auto stage = [&](int h) {
        if (h < hmax) {
            const int t   = h >> 2;
            const int th  = h & 3;
            const int kof = t * BK8 + ((th >> 1) ? 32 : 0);
            const bf16* src = (th & 1) ? baseB : baseA;
            bf16* l0 = ldsw + (h & 7) * 8192;
            GLOAD_LDS16(src + kof, l0);
            GLOAD_LDS16(src + kof + rstep, l0 + 4096);
        }
    };

    // prologue: stage halves 0..5, wait for halves 0..3
    for (int h = 0; h < 6; ++h) stage(h);
    asm volatile("s_waitcnt vmcnt(4)" ::: "memory");
    __builtin_amdgcn_s_barrier();

    const int rowk = lane & 15;
    const int kc   = lane >> 4;          // logical 8-elem k-chunk 0..3
    // swizzled chunk offset: (row>>1)&3 == (rowk>>1)&3 for all rows we touch
    // (wr, wc, m*16, +64 are all ≡ 0 mod 8), so it is a per-lane constant.
    const int kxor = (kc ^ ((rowk >> 1) & 3)) * 8;

#define LDSFRAG(slot, row) (*(const bf16x8*)&lds[(slot) * 8192 + (row) * 32 + kxor])

    bf16x8 a[4], b[4], a2[4], b2[4];
    // initial reads: tile 0 phase 1 operands (slots 0 = A-kh0, 1 = B-kh0)
#pragma unroll
    for (int m = 0; m < 4; ++m) a[m] = LDSFRAG(0, wr + m * 16 + rowk);
#pragma unroll
    for (int n = 0; n < 4; ++n) b[n] = LDSFRAG(1, wc + n * 16 + rowk);

    for (int t = 0; t < NT; ++t) {
        const int h0  = 4 * t;
        const int sA0 = (h0 + 0) & 7;
        const int sA1 = (h0 + 2) & 7, sB1 = (h0 + 3) & 7;

        // ---- phase 1: acc_lo += a(kh0,Mlow) x b(kh0); prefetch a2 = kh0,Mhigh
        stage(h0 + 6);
#pragma unroll
        for (int m = 0; m < 4; ++m) a2[m] = LDSFRAG(sA0, wr + 64 + m * 16 + rowk);
        __builtin_amdgcn_sched_barrier(0);
        __builtin_amdgcn_s_setprio(1);
#pragma unroll
        for (int m = 0; m < 4; ++m)
#pragma unroll
            for (int n = 0; n < 4; ++n)
                acc[m][n] = __builtin_amdgcn_mfma_f32_16x16x32_bf16(a[m], b[n], acc[m][n], 0, 0, 0);
        __builtin_amdgcn_s_setprio(0);
        __builtin_amdgcn_s_barrier();

        // ---- phase 2: acc_hi += a2 x b; prefetch a = kh1,Mlow and b2 = kh1
        stage(h0 + 7);
#pragma unroll
        for (int m = 0; m < 4; ++m) a[m] = LDSFRAG(sA1, wr + m * 16 + rowk);
#pragma unroll
        for (int n = 0; n < 4; ++n) b2[n] = LDSFRAG(sB1, wc + n * 16 + rowk);
        __builtin_amdgcn_sched_barrier(0);
        __builtin_amdgcn_s_setprio(1);
#pragma unroll
        for (int m = 0; m < 4; ++m)
#pragma unroll
            for (int n = 0; n < 4; ++n)
                acc[4 + m][n] = __builtin_amdgcn_mfma_f32_16x16x32_bf16(a2[m], b[n], acc[4 + m][n], 0, 0, 0);
        __builtin_amdgcn_s_setprio(0);
        __builtin_amdgcn_s_barrier();

        // ---- phase 3: acc_lo += a x b2; prefetch a2 = kh1,Mhigh
        stage(h0 + 8);
#pragma unroll
        for (int m = 0; m < 4; ++m) a2[m] = LDSFRAG(sA1, wr + 64 + m * 16 + rowk);
        __builtin_amdgcn_sched_barrier(0);
        __builtin_amdgcn_s_setprio(1);
#pragma unroll
        for (int m = 0; m < 4; ++m)
#pragma unroll
            for (int n = 0; n < 4; ++n)
                acc[m][n] = __builtin_amdgcn_mfma_f32_16x16x32_bf16(a[m], b2[n], acc[m][n], 0, 0, 0);
        __builtin_amdgcn_s_setprio(0);
        __builtin_amdgcn_s_barrier();

        // ---- phase 4: acc_hi += a2 x b2; vmcnt; prefetch next tile's a,b
        stage(h0 + 9);
        __builtin_amdgcn_sched_barrier(0);
        __builtin_amdgcn_s_setprio(1);
#pragma unroll
        for (int m = 0; m < 4; ++m)
#pragma unroll
            for (int n = 0; n < 4; ++n)
                acc[4 + m][n] = __builtin_amdgcn_mfma_f32_16x16x32_bf16(a2[m], b2[n], acc[4 + m][n], 0, 0, 0);
        __builtin_amdgcn_s_setprio(0);
        // counted per-tile wait: halves <= 4t+7 landed; never drain mid-loop
        if (t < NT - 2)       asm volatile("s_waitcnt vmcnt(4)" ::: "memory");
        else if (t == NT - 2) asm volatile("s_waitcnt vmcnt(0)" ::: "memory");
        if (t + 1 < NT) {
            const int nA0 = (h0 + 4) & 7, nB0 = (h0 + 5) & 7;
#pragma unroll
            for (int m = 0; m < 4; ++m) a[m] = LDSFRAG(nA0, wr + m * 16 + rowk);
#pragma unroll
            for (int n = 0; n < 4; ++n) b[n] = LDSFRAG(nB0, wc + n * 16 + rowk);
        }
        __builtin_amdgcn_s_barrier();
    }
#undef LDSFRAG

    // epilogue: C/D layout col = lane&15, row = (lane>>4)*4 + r
    const int ccol = lane & 15;
    const int crow = (lane >> 4) * 4;
#pragma unroll
    for (int mf = 0; mf < 8; ++mf) {
#pragma unroll
        for (int nf = 0; nf < 4; ++nf) {
            float* cp = C + (size_t)(bm + wr + mf * 16 + crow) * OUT_F + (bcol + wc + nf * 16 + ccol);
#pragma unroll
            for (int r = 0; r < 4; ++r)
                cp[(size_t)r * OUT_F] = acc[mf][nf][r];
        }
    }
}

// -------------------------------------------------------------------------
// Kernel 4: sum nPart partial C buffers into out (float4-vectorized).
// -------------------------------------------------------------------------
__global__ __launch_bounds__(256) void reduce_partials(const float4* __restrict__ P,
                                                       float4* __restrict__ out,
                                                       int nPart, int n4)
{
    const int stride = gridDim.x * 256;
    for (int i = blockIdx.x * 256 + threadIdx.x; i < n4; i += stride) {
        float4 s = P[i];
        for (int p = 1; p < nPart; ++p) {
            const float4 q = P[(size_t)p * n4 + i];
            s.x += q.x; s.y += q.y; s.z += q.z; s.w += q.w;
        }
        out[i] = s;
    }
}

// -------------------------------------------------------------------------
extern "C" void kernel_launch(void* const* d_in, const int* in_sizes, int n_in,
                              void* d_out, int out_size, void* d_ws, size_t ws_size,
                              hipStream_t stream)
{
    const float* x  = (const float*)d_in[0];   // (4096,1024)
    const float* bw = (const float*)d_in[1];   // (1024,1024)
    const float* sw = (const float*)d_in[2];   // (1024,1024,8)
    const float* sc = (const float*)d_in[3];   // (1024,1024)
    const float* gr = (const float*)d_in[4];   // (1024,12) all rows equal
    float* out = (float*)d_out;                // (4096,1024)

    bf16* A = (bf16*)d_ws;                          // 4096*9216*2 = 75.5 MB
    bf16* W = A + (size_t)BATCH * KDIM;             // 1024*9216*2 = 18.9 MB
    float* parts = (float*)(W + (size_t)OUT_F * KDIM);

    const size_t baseBytes = ((size_t)BATCH + OUT_F) * KDIM * sizeof(bf16);
    const size_t cBytes    = (size_t)BATCH * OUT_F * sizeof(float);

    // split-K degree, gated on workspace size (ws_size fixed -> deterministic)
    int split = 1;
    if (ws_size >= baseBytes + 4 * cBytes)      split = 4;
    else if (ws_size >= baseBytes + 2 * cBytes) split = 2;

    build_A<<<(BATCH * IN_F) / 256, 256, 0, stream>>>(x, gr, A);
    pack_W<<<(OUT_F * IN_F) / 256, 256, 0, stream>>>(bw, sw, sc, W);

    const int nblk = (BATCH / BM8) * (OUT_F / BN8) * split;   // 64*split
    float* gemmOut = (split > 1) ? parts : out;
    gemm8<<<nblk, 512, 0, stream>>>(A, W, gemmOut, KDIM / split);

    if (split > 1) {
        const int n4 = BATCH * OUT_F / 4;
        reduce_partials<<<2048, 256, 0, stream>>>((const float4*)parts, (float4*)out,
                                                  split, n4);
    }
}